// Round 7
// baseline (274.830 us; speedup 1.0000x reference)
//
#include <hip/hip_runtime.h>
#include <math.h>

#define NLAT 64
#define NLON 128
#define HID  256
#define NSTA 1024
#define TG   16    // grid points (lons) per block = MFMA M
#define SC   256   // station chunk (512-thread block)
#define NCHUNK (NSTA / SC)
#define NGRP 32    // station groups in phase A (512 threads / TG)
#define TABN 4096
#define TABW 4.5f

#define LOG2E 1.4426950408889634f
#define LN2   0.69314718055994531f

typedef float f32x4 __attribute__((ext_vector_type(4)));
typedef _Float16 f16x8 __attribute__((ext_vector_type(8)));

// accurate gelu for table build (A&S 7.1.26, |erf err| <= 1.5e-7)
__device__ __forceinline__ float gelu_ref(float x) {
    const float p  = 0.3275911f;
    const float a1 = 0.254829592f, a2 = -0.284496736f, a3 = 1.421413741f,
                a4 = -1.453152027f, a5 = 1.061405429f;
    float z  = x * 0.70710678118654752f;
    float az = fabsf(z);
    float t  = __builtin_amdgcn_rcpf(fmaf(p, az, 1.0f));
    float poly = fmaf(fmaf(fmaf(fmaf(a5, t, a4), t, a3), t, a2), t, a1) * t;
    float e  = __builtin_amdgcn_exp2f(az * az * -LOG2E);
    float r  = fmaf(-poly, e, 1.0f);
    float erfz = copysignf(r, z);
    float hx = 0.5f * x;
    return fmaf(hx, erfz, hx);
}

// ---- Kernel 0: feats [b][s][d] f32 -> F^T hi/lo [b][d][s] f16 (split for precision)
// 64x64 tiles: coalesced float4 global reads, f16x8 vectorized writes.
__global__ __launch_bounds__(256)
void cvt_kernel(const float* __restrict__ feats, _Float16* __restrict__ fhi,
                _Float16* __restrict__ flo) {
    __shared__ float tile[64][68];
    const int blk = blockIdx.x;            // b(2) * st16 * dt(4)
    const int b  = blk >> 6;
    const int st = (blk >> 2) & 15;        // station tile of 64
    const int dt = blk & 3;                // d tile of 64
    {
        const int dq = threadIdx.x & 15;   // float4 col
        const int sr = threadIdx.x >> 4;   // 0..15
#pragma unroll
        for (int k = 0; k < 4; ++k) {
            int s = k * 16 + sr;
            float4 vv = *(const float4*)
                &feats[((size_t)(b * NSTA + st * 64 + s)) * HID + dt * 64 + dq * 4];
            *(float4*)&tile[s][dq * 4] = vv;
        }
    }
    __syncthreads();
    const int d  = threadIdx.x >> 2;       // 0..63
    const int sg = threadIdx.x & 3;        // station subgroup of 16
    f16x8 h8[2], l8[2];
#pragma unroll
    for (int k = 0; k < 16; ++k) {
        float v = tile[sg * 16 + k][d];
        _Float16 h = (_Float16)v;
        h8[k >> 3][k & 7] = h;
        l8[k >> 3][k & 7] = (_Float16)(v - (float)h);
    }
    const size_t o = ((size_t)(b * HID + dt * 64 + d)) * NSTA + st * 64 + sg * 16;
    *(f16x8*)&fhi[o]     = h8[0];
    *(f16x8*)&fhi[o + 8] = h8[1];
    *(f16x8*)&flo[o]     = l8[0];
    *(f16x8*)&flo[o + 8] = l8[1];
}

// ---- Main kernel: fused score MLP (LUT gelu) + online softmax + MFMA weighted sum
// 512 threads = 8 waves: phase C k-split across wave pairs, merged in epilogue.
__global__ __launch_bounds__(512, 8)
void s2g_kernel(const float* __restrict__ coords,  // [2][1024][3]
                const float* __restrict__ maskp,   // [2][1024]
                const float* __restrict__ W1,      // [3][32]
                const float* __restrict__ b1,      // [32]
                const float* __restrict__ W2,      // [32]
                const float* __restrict__ b2p,     // [1]
                const _Float16* __restrict__ fhi,  // [2][256][1024]
                const _Float16* __restrict__ flo,  // [2][256][1024]
                float* __restrict__ out)           // [2][256][64][128]
{
    __shared__ __align__(16) float gtab[TABN];     // 16 KB; reused as epilogue buffer
    __shared__ __align__(16) f16x8 fragAh[512];    // 8 KB: P f16 in MFMA A-frag order
    __shared__ __align__(16) float slat[SC], slon[SC], smask[SC];
    __shared__ float4 wpack[32];                   // (W1row0, W1row1, W1row2, b1)
    __shared__ float w2s[32];
    __shared__ __align__(16) float maxbuf[NGRP * TG], psum[NGRP * TG];
    __shared__ __align__(16) float mS[TG], lS[TG], alphaS[TG];

    const int tid  = threadIdx.x;
    const int blk  = blockIdx.x & 511;     // 64 lat * 8 lon-blocks
    const int b    = blockIdx.x >> 9;      // batch
    const int lat  = blk >> 3;
    const int lon0 = (blk & 7) * TG;

    const float latv = -90.0f + (180.0f / 63.0f) * (float)lat;

    // table: cell k covers [-W + k*h, -W + (k+1)*h), value at cell center
    const float TH = 2.0f * TABW / (float)TABN;
#pragma unroll
    for (int k = tid; k < TABN; k += 512) {
        float x = -TABW + ((float)k + 0.5f) * TH;
        gtab[k] = gelu_ref(x) - fmaxf(x, 0.0f);
    }
    if (tid < 32) {
        wpack[tid] = make_float4(W1[tid], W1[32 + tid], W1[64 + tid], b1[tid]);
        w2s[tid]   = W2[tid];
        if (tid < TG) { mS[tid] = -1.0e30f; lS[tid] = 0.0f; }
    }
    const float b2 = b2p[0];

    // phase A mapping: thread -> (grid col gA, station group sgrp of 8)
    const int gA   = tid & (TG - 1);
    const int sgrp = tid >> 4;             // 0..31
    const float lonvA = -180.0f + (360.0f / 127.0f) * (float)(lon0 + gA);

    // phase C mapping: wave wv: kc-half = wv>>2, d-range = (wv&3)*64
    const int lane = tid & 63;
    const int wv   = tid >> 6;             // 0..7
    const int kc0  = (wv >> 2) * 4;        // 0 or 4
    const int dsel = (wv & 3) * 64;

    f32x4 acc[4];
#pragma unroll
    for (int t = 0; t < 4; ++t) acc[t] = (f32x4){0.0f, 0.0f, 0.0f, 0.0f};

    const float* cbase = coords + (size_t)b * NSTA * 3;
    const float* mbase = maskp  + (size_t)b * NSTA;
    const _Float16* fhb = fhi + (size_t)b * HID * NSTA;
    const _Float16* flb = flo + (size_t)b * HID * NSTA;

    const float ISCALE = (float)TABN / (2.0f * TABW);   // entries per unit
    const float IOFF   = (float)TABN * 0.5f;            // +W*ISCALE

    for (int c = 0; c < NCHUNK; ++c) {
        const int s0 = c * SC;
        __syncthreads();   // table/weights visible (c=0); prev MFMA done with frags
        if (tid < SC) {
            slat[tid]  = cbase[(size_t)(s0 + tid) * 3 + 0];
            slon[tid]  = cbase[(size_t)(s0 + tid) * 3 + 1];
            smask[tid] = mbase[s0 + tid];
        }
        __syncthreads();

        // ---- Phase A: scores for 8 stations at grid col gA (LUT gelu)
        float dist[8], dlat[8], dlon[8], v[8];
#pragma unroll
        for (int i = 0; i < 8; ++i) {
            int s = sgrp * 8 + i;
            float dla = slat[s] - latv;
            float dlo = slon[s] - lonvA;
            dlat[i] = dla;
            dlon[i] = dlo;
            dist[i] = sqrtf(fmaf(dla, dla, fmaf(dlo, dlo, 1e-6f)));
            v[i] = b2;
        }
#pragma unroll 2
        for (int j = 0; j < 32; ++j) {
            float4 wj = wpack[j];
            float  w2 = w2s[j];
#pragma unroll
            for (int i = 0; i < 8; ++i) {
                float pre = fmaf(wj.x, dist[i], fmaf(wj.y, dlat[i], fmaf(wj.z, dlon[i], wj.w)));
                float cl  = fminf(fmaxf(pre, -TABW), 4.4999f);   // v_med3_f32
                int  idx  = (int)fmaf(cl, ISCALE, IOFF);         // trunc -> cell
                float ge  = fmaxf(pre, 0.0f) + gtab[idx];        // relu + LUT residual
                v[i] = fmaf(w2, ge, v[i]);
            }
        }
        float lmax = -3.0e38f;
#pragma unroll
        for (int i = 0; i < 8; ++i) {
            int s = sgrp * 8 + i;
            float x  = v[i];
            float ax = fabsf(x);
            float e  = __builtin_amdgcn_exp2f(-ax * LOG2E);
            float sp = fmaxf(x, 0.0f) + __builtin_amdgcn_logf(1.0f + e) * LN2;
            v[i] = sp * smask[s];
            lmax = fmaxf(lmax, v[i]);
        }
        maxbuf[sgrp * TG + gA] = lmax;
        __syncthreads();

        // ---- B1: running max + rescale factor per grid col
        if (tid < TG) {
            float cm = maxbuf[tid];
#pragma unroll
            for (int k = 1; k < NGRP; ++k) cm = fmaxf(cm, maxbuf[k * TG + tid]);
            float mold = mS[tid];
            float mnew = fmaxf(mold, cm);
            alphaS[tid] = __builtin_amdgcn_exp2f((mold - mnew) * LOG2E);
            mS[tid] = mnew;
        }
        __syncthreads();

        // ---- B2: p = exp(v-m) -> f16, A-frag layout; sum fp32 p
        {
            float m  = mS[gA];
            float ps = 0.0f;
            f16x8 fh;
#pragma unroll
            for (int i = 0; i < 8; ++i) {
                float p = __builtin_amdgcn_exp2f((v[i] - m) * LOG2E);
                fh[i] = (_Float16)p;
                ps += p;
            }
            // station kc-block sgrp>>2, lane ((sgrp&3)<<4)|gA, frag elem i
            fragAh[((sgrp >> 2) << 6) + (((sgrp & 3) << 4) | gA)] = fh;
            psum[sgrp * TG + gA] = ps;
        }
        __syncthreads();

        // ---- B3: denominator update (runs alongside phase C)
        if (tid < TG) {
            float t = 0.0f;
#pragma unroll
            for (int k = 0; k < NGRP; ++k) t += psum[k * TG + tid];
            lS[tid] = lS[tid] * alphaS[tid] + t;
        }

        // ---- Phase C: rescale accumulators (rows m = (lane>>4)*4+reg), MFMA (k-split)
        {
            const f32x4 al = *(const f32x4*)&alphaS[(lane >> 4) * 4];
#pragma unroll
            for (int t = 0; t < 4; ++t) acc[t] = acc[t] * al;

            const int srow = (lane >> 4) * 8;
            const int dbase = dsel + (lane & 15);
#pragma unroll
            for (int kc = 0; kc < 4; ++kc) {
                f16x8 a = fragAh[((kc0 + kc) << 6) + lane];
#pragma unroll
                for (int t = 0; t < 4; ++t) {
                    const size_t off = (size_t)(dbase + t * 16) * NSTA +
                                       s0 + (kc0 + kc) * 32 + srow;
                    f16x8 bh = *(const f16x8*)(fhb + off);
                    f16x8 bl = *(const f16x8*)(flb + off);
                    acc[t] = __builtin_amdgcn_mfma_f32_16x16x32_f16(a, bh, acc[t], 0, 0, 0);
                    acc[t] = __builtin_amdgcn_mfma_f32_16x16x32_f16(a, bl, acc[t], 0, 0, 0);
                }
            }
        }
    }
    __syncthreads();   // lS final; gtab no longer needed

    // ---- epilogue: merge kc-halves (waves wv and wv+4 share d-range), then store
    {
        f32x4* red = reinterpret_cast<f32x4*>(gtab);   // 16 KB overlay: [4 dsel][4 t][64 lane]
        if (wv >= 4) {
#pragma unroll
            for (int t = 0; t < 4; ++t) red[(((wv & 3) * 4 + t) << 6) + lane] = acc[t];
        }
        __syncthreads();
        if (wv < 4) {
            const float4 l4 = *(const float4*)&lS[(lane >> 4) * 4];
            const float4 rl = make_float4(1.0f / l4.x, 1.0f / l4.y, 1.0f / l4.z, 1.0f / l4.w);
            const int m0 = (lane >> 4) * 4;
            const size_t gbase = (size_t)lat * NLON + lon0 + m0;
#pragma unroll
            for (int t = 0; t < 4; ++t) {
                f32x4 s = acc[t] + red[((wv * 4 + t) << 6) + lane];
                const int d = dsel + t * 16 + (lane & 15);
                float4 o;
                o.x = s.x * rl.x;
                o.y = s.y * rl.y;
                o.z = s.z * rl.z;
                o.w = s.w * rl.w;
                *reinterpret_cast<float4*>(out + ((size_t)(b * HID + d)) * (NLAT * NLON) + gbase) = o;
            }
        }
    }
}

extern "C" void kernel_launch(void* const* d_in, const int* in_sizes, int n_in,
                              void* d_out, int out_size, void* d_ws, size_t ws_size,
                              hipStream_t stream) {
    const float* feats  = (const float*)d_in[0];
    const float* coords = (const float*)d_in[1];
    const float* maskp  = (const float*)d_in[2];
    const float* W1     = (const float*)d_in[3];
    const float* b1     = (const float*)d_in[4];
    const float* W2     = (const float*)d_in[5];
    const float* b2     = (const float*)d_in[6];
    float* out          = (float*)d_out;

    _Float16* fhi = (_Float16*)d_ws;                     // [2][256][1024] = 1 MB
    _Float16* flo = fhi + (size_t)2 * HID * NSTA;        // [2][256][1024] = 1 MB

    hipLaunchKernelGGL(cvt_kernel, dim3(128), dim3(256), 0, stream, feats, fhi, flo);
    hipLaunchKernelGGL(s2g_kernel, dim3(1024), dim3(512), 0, stream,
                       coords, maskp, W1, b1, W2, b2, fhi, flo, out);
}